// Round 3
// baseline (676.651 us; speedup 1.0000x reference)
//
#include <hip/hip_runtime.h>
#include <stdint.h>
#include <math.h>

#define N_B 4
#define T_S 4096
#define D_M 1024
#define H_M 1536
#define NT  (N_B * T_S)   // 16384
#define G2  (2 * H_M)     // 3072
#define LCH 64            // timesteps per chunk
#define NCH 64            // chunks (LCH*NCH == T_S)

typedef __attribute__((ext_vector_type(8))) short short8;
typedef __attribute__((ext_vector_type(4))) float floatx4;

__device__ __forceinline__ unsigned short f2bf(float f) {
  unsigned u = __float_as_uint(f);
  u += 0x7fff + ((u >> 16) & 1);            // RNE
  return (unsigned short)(u >> 16);
}
__device__ __forceinline__ float bf2f(unsigned short u) {
  return __uint_as_float(((unsigned)u) << 16);
}
__device__ __forceinline__ float bf_lo(unsigned p) { return __uint_as_float(p << 16); }
__device__ __forceinline__ float bf_hi(unsigned p) { return __uint_as_float(p & 0xffff0000u); }
__device__ __forceinline__ unsigned bf_pack(float lo, float hi) {
  return ((unsigned)f2bf(lo)) | (((unsigned)f2bf(hi)) << 16);
}
__device__ __forceinline__ float sigmoidf_(float x) { return 1.f / (1.f + __expf(-x)); }
__device__ __forceinline__ float softplusf_(float x) {
  return (x > 20.f) ? x : log1pf(__expf(x));
}
__device__ __forceinline__ float geluf_(float x) {
  return 0.5f * x * (1.f + erff(x * 0.70710678118654752f));
}

// ---------------- zero-fill fallback (diagnostic if ws_size too small) ----------------
__global__ void zero_out(float* __restrict__ out, int n) {
  int i = blockIdx.x * 256 + threadIdx.x;
  if (i < n) out[i] = 0.f;
}

// ---------------- fused f32 -> bf16 conversion of x, Win, Wg (one launch) ----------------
#define N4_X   (NT * D_M / 4)          // 4,194,304
#define N4_WIN (G2 * D_M / 4)          //   786,432
#define N4_WG  (G2 * H_M / 4)          // 1,179,648
__global__ void cvt3_bf16(const float* __restrict__ x, unsigned short* __restrict__ x16,
                          const float* __restrict__ win, unsigned short* __restrict__ win16,
                          const float* __restrict__ wg, unsigned short* __restrict__ wg16) {
  int i = blockIdx.x * 256 + threadIdx.x;
  const float* in; unsigned short* out;
  if (i < N4_X)                { in = x;   out = x16; }
  else if (i < N4_X + N4_WIN)  { in = win; out = win16; i -= N4_X; }
  else if (i < N4_X + N4_WIN + N4_WG) { in = wg; out = wg16; i -= N4_X + N4_WIN; }
  else return;
  float4 v = ((const float4*)in)[i];
  ushort4 o;
  o.x = f2bf(v.x); o.y = f2bf(v.y); o.z = f2bf(v.z); o.w = f2bf(v.w);
  ((ushort4*)out)[i] = o;
}

__global__ void cvt_bf16(const float* __restrict__ in, unsigned short* __restrict__ out, int n4) {
  int i = blockIdx.x * 256 + threadIdx.x;
  if (i >= n4) return;
  float4 v = ((const float4*)in)[i];
  ushort4 o;
  o.x = f2bf(v.x); o.y = f2bf(v.y); o.z = f2bf(v.z); o.w = f2bf(v.w);
  ((ushort4*)out)[i] = o;
}

// ---------------- bf16 MFMA GEMM, 256x256 tile, double-buffered 4-phase schedule ------
// C[m,n] = sum_k A[m,k]*B[n,k] (+bias[n]).  512 threads = 8 waves (2 Mx4 N), BK=64.
// LDS 128 KiB: [buf 2][slot 4][256 rows x 32 k] bf16; slots 0=A.kh0 1=A.kh1 2=B.kh0 3=B.kh1.
// r2 post-mortem: reads AFTER the pre-MFMA barrier exposed ~150 cy LDS latency per phase
// (MfmaUtil stuck at 46.7%). r3 = m201 phase order: reads at phase TOP (before the barrier)
// so latency drains under barrier skew + previous phase's in-flight MFMAs. Full double
// buffer (parity d = t&1) removes every read/restage alias, making top-reads legal.
// Per tile t (d = t&1, dn = d^1), 4 phases x 16 MFMA, 2 barriers each (= m201 cadence):
//   P1: read af<-slot0[d] (8 b128) + bfr[0..3]<-slot2[d] (4); stage A.kh0(t+1)->slot0[dn];
//       bar; lgkm0; MFMA j=0,1; bar
//   P2: stage B.kh0(t+1)->slot2[dn]; vmcnt(4) [slot1[d],slot3[d] landed]; bar; MFMA j=2,3; bar
//   P3: read af<-slot1[d] + bfr<-slot3[d]; stage A.kh1(t+1)->slot1[dn];
//       bar; lgkm0; MFMA j=0,1 (K-accumulate); bar
//   P4: stage B.kh1(t+1)->slot3[dn]; vmcnt(4) [slot0[dn],slot2[dn] landed]; bar; MFMA j=2,3; bar
// Ledger (2 loads/stage-unit, issue order A0,B0,A1,B1 per tile): at each wait exactly 8
// outstanding, oldest 4 = the units needed 1 phase later -> vmcnt(4). Never drains in the
// main loop; vmcnt(0) only at last tile's P2. Read-hoist across barriers is fenced by the
// interposed asm-"memory" waitcnts. Raw s_barrier, s_setprio(1) around MFMA (T5).
// Bank swizzle (r2-proven, 0 conflicts): phys slot = kq ^ ((fr>>1)&3) on reads; global
// source pre-swizzled g=(tid&3)^((tid>>3)&3) with linear LDS dest (rule #21).
// XCD swizzle (r1-proven: FETCH 234->141 MB): bijective, nwg%8==0 for all shapes.
#define TM 256
#define TN 256

__device__ __forceinline__ void stage16(const unsigned short* g, unsigned short* l) {
  __builtin_amdgcn_global_load_lds((__attribute__((address_space(1))) void*)g,
                                   (__attribute__((address_space(3))) void*)l, 16, 0, 0);
}

template<bool BIAS, bool OUT_BF16, bool SPLIT>
__global__ __launch_bounds__(512, 2)
void gemm_bt8(const unsigned short* __restrict__ A,
              const unsigned short* __restrict__ B,
              void* __restrict__ Cv, void* __restrict__ Cv2,
              const float* __restrict__ bias,
              int N, int K) {
  __shared__ __align__(16) unsigned short lds[2][4][8192];   // 128 KiB
  const int tid  = threadIdx.x;
  const int lane = tid & 63;
  const int wave = tid >> 6;
  const int wr = wave >> 2;                  // 0..1  (M half of tile)
  const int wc = wave & 3;                   // 0..3  (N quarter of tile)

  // bijective XCD-aware block swizzle (nwg % 8 == 0 for all shapes used)
  const int gx  = gridDim.x;
  const int nwg = gx * gridDim.y;
  const int bid = blockIdx.y * gx + blockIdx.x;
  const int cpx = nwg >> 3;
  const int swz = (bid & 7) * cpx + (bid >> 3);
  const int bm = (swz / gx) * TM;
  const int bn = (swz % gx) * TN;

  floatx4 acc[8][4];
#pragma unroll
  for (int i = 0; i < 8; i++)
#pragma unroll
    for (int j = 0; j < 4; j++)
      acc[i][j] = (floatx4){0.f, 0.f, 0.f, 0.f};

  // ---- staging: one k-half unit = 256 rows x 32 k = 1024 x 16B chunks; thread does 2.
  // chunk c = tid + 512u -> row r = c>>2 (= tid>>2 + 128u), phys slot sl = c&3.
  // logical k-group fetched: g = sl ^ ((r>>1)&3) = (tid&3) ^ ((tid>>3)&3)  (u-invariant).
  const int r0_ = tid >> 2;                  // 0..127
  const int g8  = ((tid & 3) ^ ((tid >> 3) & 3)) * 8;
  const unsigned short* Ag1 = A + (size_t)(bm + r0_)       * K + g8;
  const unsigned short* Ag2 = A + (size_t)(bm + r0_ + 128) * K + g8;
  const unsigned short* Bg1 = B + (size_t)(bn + r0_)       * K + g8;
  const unsigned short* Bg2 = B + (size_t)(bn + r0_ + 128) * K + g8;
  const int ld1 = tid * 8;                   // elem offset in slot
  const int ld2 = ld1 + 4096;

#define STAGE_A(bu, kh, kb) do { \
    stage16(Ag1 + (kb) + (kh) * 32, &lds[bu][kh][ld1]); \
    stage16(Ag2 + (kb) + (kh) * 32, &lds[bu][kh][ld2]); } while (0)
#define STAGE_B(bu, kh, kb) do { \
    stage16(Bg1 + (kb) + (kh) * 32, &lds[bu][2 + (kh)][ld1]); \
    stage16(Bg2 + (kb) + (kh) * 32, &lds[bu][2 + (kh)][ld2]); } while (0)

  // ---- fragment read bases: lane (fr, kq); phys slot = kq ^ ((fr>>1)&3)
  const int fr = lane & 15;
  const int kq = lane >> 4;
  const int sx = (kq ^ ((fr >> 1) & 3)) * 8;
  const int abase = (wr * 128 + fr) * 32 + sx;   // + i*512
  const int bbase = (wc * 64 + fr) * 32 + sx;    // + j*512

  const int nt = K >> 6;
  short8 af[8], bfr[4];

  // prologue: tile 0 -> buf 0, issue order matches steady-state ledger (A0,B0,A1,B1)
  STAGE_A(0, 0, 0); STAGE_B(0, 0, 0); STAGE_A(0, 1, 0); STAGE_B(0, 1, 0);
  asm volatile("s_waitcnt vmcnt(4)" ::: "memory");   // slot0[0], slot2[0] landed
  __builtin_amdgcn_s_barrier();

  for (int t = 0; t < nt; ++t) {
    const int d  = t & 1;
    const int dn = d ^ 1;
    const int kn = (t + 1) << 6;
    const bool st = (t + 1 < nt);

    // ---- P1: reads at top (kh0), stage A.kh0(t+1) ----
#pragma unroll
    for (int i = 0; i < 8; ++i) af[i]  = *(const short8*)(&lds[d][0][abase + i * 512]);
#pragma unroll
    for (int j = 0; j < 4; ++j) bfr[j] = *(const short8*)(&lds[d][2][bbase + j * 512]);
    if (st) STAGE_A(dn, 0, kn);
    __builtin_amdgcn_s_barrier();
    asm volatile("s_waitcnt lgkmcnt(0)" ::: "memory");
    __builtin_amdgcn_s_setprio(1);
#pragma unroll
    for (int i = 0; i < 8; ++i)
#pragma unroll
      for (int j = 0; j < 2; ++j)
        acc[i][j] = __builtin_amdgcn_mfma_f32_16x16x32_bf16(af[i], bfr[j], acc[i][j], 0, 0, 0);
    __builtin_amdgcn_s_setprio(0);
    __builtin_amdgcn_s_barrier();

    // ---- P2: pure MFMA (af, bfr[2..3] held); stage B.kh0(t+1); wait for kh1(t) ----
    if (st) STAGE_B(dn, 0, kn);
    if (st) { asm volatile("s_waitcnt vmcnt(4)" ::: "memory"); }  // slot1[d], slot3[d]
    else    { asm volatile("s_waitcnt vmcnt(0)" ::: "memory"); }
    __builtin_amdgcn_s_barrier();
    __builtin_amdgcn_s_setprio(1);
#pragma unroll
    for (int i = 0; i < 8; ++i)
#pragma unroll
      for (int j = 0; j < 2; ++j)
        acc[i][2 + j] = __builtin_amdgcn_mfma_f32_16x16x32_bf16(af[i], bfr[2 + j], acc[i][2 + j], 0, 0, 0);
    __builtin_amdgcn_s_setprio(0);
    __builtin_amdgcn_s_barrier();

    // ---- P3: reads at top (kh1), stage A.kh1(t+1) ----
#pragma unroll
    for (int i = 0; i < 8; ++i) af[i]  = *(const short8*)(&lds[d][1][abase + i * 512]);
#pragma unroll
    for (int j = 0; j < 4; ++j) bfr[j] = *(const short8*)(&lds[d][3][bbase + j * 512]);
    if (st) STAGE_A(dn, 1, kn);
    __builtin_amdgcn_s_barrier();
    asm volatile("s_waitcnt lgkmcnt(0)" ::: "memory");
    __builtin_amdgcn_s_setprio(1);
#pragma unroll
    for (int i = 0; i < 8; ++i)
#pragma unroll
      for (int j = 0; j < 2; ++j)
        acc[i][j] = __builtin_amdgcn_mfma_f32_16x16x32_bf16(af[i], bfr[j], acc[i][j], 0, 0, 0);
    __builtin_amdgcn_s_setprio(0);
    __builtin_amdgcn_s_barrier();

    // ---- P4: pure MFMA; stage B.kh1(t+1); wait for kh0(t+1) ----
    if (st) STAGE_B(dn, 1, kn);
    if (st) { asm volatile("s_waitcnt vmcnt(4)" ::: "memory"); }  // slot0[dn], slot2[dn]
    __builtin_amdgcn_s_barrier();
    __builtin_amdgcn_s_setprio(1);
#pragma unroll
    for (int i = 0; i < 8; ++i)
#pragma unroll
      for (int j = 0; j < 2; ++j)
        acc[i][2 + j] = __builtin_amdgcn_mfma_f32_16x16x32_bf16(af[i], bfr[2 + j], acc[i][2 + j], 0, 0, 0);
    __builtin_amdgcn_s_setprio(0);
    __builtin_amdgcn_s_barrier();
  }
#undef STAGE_A
#undef STAGE_B

  // C/D layout (m89-verified): col = lane&15, row = (lane>>4)*4 + reg
  // stores row-major (j innermost): 64B C-line halves issued back-to-back (r2-proven,
  // WRITE_SIZE == output size).
  const int half  = SPLIT ? (N >> 1) : N;
  const bool hi   = SPLIT && (bn >= half);
  void* Cb        = hi ? Cv2 : Cv;
  const int coff  = hi ? half : 0;
  const int cn = lane & 15;
  const int rb = (lane >> 4) * 4;
  float bv[4];
#pragma unroll
  for (int j = 0; j < 4; ++j)
    bv[j] = BIAS ? bias[bn + wc * 64 + j * 16 + cn] : 0.f;
  const int col0 = bn + wc * 64 + cn - coff;
#pragma unroll
  for (int i = 0; i < 8; ++i) {
    const int row0 = bm + wr * 128 + i * 16 + rb;
#pragma unroll
    for (int r = 0; r < 4; ++r) {
      const size_t rowb = (size_t)(row0 + r) * half + col0;
#pragma unroll
      for (int j = 0; j < 4; ++j) {
        float v = acc[i][j][r] + bv[j];
        if (OUT_BF16) ((unsigned short*)Cb)[rowb + j * 16] = f2bf(v);
        else          ((float*)Cb)[rowb + j * 16] = v;
      }
    }
  }
}

// ---------------- depthwise causal conv (K=4) + bias, 2 channels/thread ----------------
__global__ void conv_dw(const unsigned int* __restrict__ xbpre2, const float* __restrict__ cw,
                        const float* __restrict__ cb, unsigned int* __restrict__ xbc2) {
  int i0 = blockIdx.x * 256 + threadIdx.x;       // pair index, 0..H_M/2-1
  int t = blockIdx.y;
  size_t nt = (size_t)blockIdx.z * T_S + t;
  const int h = 2 * i0;
  const float4 wa = ((const float4*)cw)[h];      // taps for channel h
  const float4 wb = ((const float4*)cw)[h + 1];  // taps for channel h+1
  const float2 cb2 = ((const float2*)cb)[i0];
  size_t base = nt * (H_M / 2) + i0;
  unsigned p0 = xbpre2[base];
  float aa = cb2.x + wa.w * bf_lo(p0);
  float ab = cb2.y + wb.w * bf_hi(p0);
  if (t >= 1) { unsigned p = xbpre2[base - H_M / 2];
    aa += wa.z * bf_lo(p); ab += wb.z * bf_hi(p); }
  if (t >= 2) { unsigned p = xbpre2[base - 2 * (size_t)(H_M / 2)];
    aa += wa.y * bf_lo(p); ab += wb.y * bf_hi(p); }
  if (t >= 3) { unsigned p = xbpre2[base - 3 * (size_t)(H_M / 2)];
    aa += wa.x * bf_lo(p); ab += wb.x * bf_hi(p); }
  xbc2[base] = bf_pack(aa, ab);
}

// ---------------- chunked linear scan (2 channels/thread) ----------------
__global__ void scan_A(const unsigned int* __restrict__ fg2, const unsigned int* __restrict__ xbc2,
                       const float* __restrict__ fb,
                       float2* __restrict__ cA2, float2* __restrict__ cS2) {
  int i0 = blockIdx.x * 256 + threadIdx.x;       // pair index
  int ch = blockIdx.y;
  int n = blockIdx.z;
  const float2 fb2 = ((const float2*)fb)[i0];
  const float c8a = 8.f * softplusf_(fb2.x);
  const float c8b = 8.f * softplusf_(fb2.y);
  float apa = 1.f, sa = 0.f, apb = 1.f, sb = 0.f;
  size_t r = (size_t)n * T_S + (size_t)ch * LCH;
  for (int i = 0; i < LCH; i++, r++) {
    unsigned pf = fg2[r * (G2 / 2) + i0];
    unsigned pi = fg2[r * (G2 / 2) + H_M / 2 + i0];
    unsigned px = xbc2[r * (H_M / 2) + i0];
    float alpha_a = __expf(-c8a * sigmoidf_(bf_lo(pf)));
    float alpha_b = __expf(-c8b * sigmoidf_(bf_hi(pf)));
    float beta_a = sqrtf(1.f - alpha_a * alpha_a + 1e-6f);
    float beta_b = sqrtf(1.f - alpha_b * alpha_b + 1e-6f);
    sa = alpha_a * sa + beta_a * sigmoidf_(bf_lo(pi)) * bf_lo(px);
    sb = alpha_b * sb + beta_b * sigmoidf_(bf_hi(pi)) * bf_hi(px);
    apa *= alpha_a;
    apb *= alpha_b;
  }
  size_t o = ((size_t)n * NCH + ch) * (H_M / 2) + i0;
  cA2[o] = make_float2(apa, apb);
  cS2[o] = make_float2(sa, sb);
}

// phase C: per-block prescan of chunk summaries (L2-hot) computes the carry-in,
// then replay with fused gelu(gate)*h written IN-PLACE over the gate buffer.
__global__ void scan_C(const unsigned int* __restrict__ fg2, const unsigned int* __restrict__ xbc2,
                       const float* __restrict__ fb,
                       const float2* __restrict__ cA2, const float2* __restrict__ cS2,
                       unsigned int* gateh2) {
  int i0 = blockIdx.x * 256 + threadIdx.x;
  int ch = blockIdx.y;
  int n = blockIdx.z;
  const float2 fb2 = ((const float2*)fb)[i0];
  const float c8a = 8.f * softplusf_(fb2.x);
  const float c8b = 8.f * softplusf_(fb2.y);
  float sa = 0.f, sb = 0.f;
  for (int c = 0; c < ch; c++) {
    size_t o = ((size_t)n * NCH + c) * (H_M / 2) + i0;
    float2 a = cA2[o], s = cS2[o];
    sa = a.x * sa + s.x;
    sb = a.y * sb + s.y;
  }
  size_t r = (size_t)n * T_S + (size_t)ch * LCH;
  for (int i = 0; i < LCH; i++, r++) {
    unsigned pf = fg2[r * (G2 / 2) + i0];
    unsigned pi = fg2[r * (G2 / 2) + H_M / 2 + i0];
    unsigned px = xbc2[r * (H_M / 2) + i0];
    float alpha_a = __expf(-c8a * sigmoidf_(bf_lo(pf)));
    float alpha_b = __expf(-c8b * sigmoidf_(bf_hi(pf)));
    float beta_a = sqrtf(1.f - alpha_a * alpha_a + 1e-6f);
    float beta_b = sqrtf(1.f - alpha_b * alpha_b + 1e-6f);
    sa = alpha_a * sa + beta_a * sigmoidf_(bf_lo(pi)) * bf_lo(px);
    sb = alpha_b * sb + beta_b * sigmoidf_(bf_hi(pi)) * bf_hi(px);
    unsigned pg = gateh2[r * (H_M / 2) + i0];
    gateh2[r * (H_M / 2) + i0] = bf_pack(geluf_(bf_lo(pg)) * sa, geluf_(bf_hi(pg)) * sb);
  }
}

// ---------------- launcher ----------------
// Workspace layout (S = NT*H_M*2 = 50,331,648 B; peak = 4S + 9.4 MB ≈ 210.8 MB):
//   [0,S)    gate16 (GEMM1 out, lo half) -> scan_C in-place -> gh16 (GEMM3 A)
//   [S,2S)   xbpre16 (GEMM1 out, hi half; conv in; dead after conv)
//   [S,3S)   fg16 (GEMM2 out, overwrites xbpre16 + x16/Win16)
//   [2S,..)  x16 (33.6MB) + Win16 (6.3MB), live only during GEMM1
//   [3S,4S)  xbc16 (conv out; dead after scan_C)
//   [4S,..)  Wg16 (9.4MB, dead after GEMM2) aliased by cA(1.5) + cS(1.5) + Wout16(3.1)
extern "C" void kernel_launch(void* const* d_in, const int* in_sizes, int n_in,
                              void* d_out, int out_size, void* d_ws, size_t ws_size,
                              hipStream_t stream) {
  const float* x    = (const float*)d_in[0];
  const float* Win  = (const float*)d_in[1];
  const float* cw   = (const float*)d_in[2];
  const float* cb   = (const float*)d_in[3];
  const float* Wg   = (const float*)d_in[4];
  const float* bg   = (const float*)d_in[5];
  const float* fb   = (const float*)d_in[6];
  const float* Wout = (const float*)d_in[7];
  float* out = (float*)d_out;
  (void)in_sizes; (void)n_in;

  const size_t S = (size_t)NT * H_M * 2;
  const size_t needed = 4 * S + (size_t)G2 * H_M * 2;
  if (ws_size < needed) {
    zero_out<<<(out_size + 255) / 256, 256, 0, stream>>>(out, out_size);
    return;
  }

  char* base = (char*)d_ws;
  unsigned short* gate16  = (unsigned short*)(base);            // becomes gh16 in-place
  unsigned short* xbpre16 = (unsigned short*)(base + S);
  unsigned short* fg16    = (unsigned short*)(base + S);        // [S,3S) after conv
  unsigned short* x16     = (unsigned short*)(base + 2 * S);    // live during GEMM1 only
  unsigned short* Win16   = (unsigned short*)(base + 2 * S + (size_t)NT * D_M * 2);
  unsigned short* xbc16   = (unsigned short*)(base + 3 * S);
  unsigned short* Wg16    = (unsigned short*)(base + 4 * S);    // dead after GEMM2
  float* cA    = (float*)(base + 4 * S);                        // aliases Wg16 (after GEMM2)
  float* cS    = cA + (size_t)N_B * NCH * H_M;
  unsigned short* Wout16  = (unsigned short*)(cS + (size_t)N_B * NCH * H_M);

  // fused bf16 conversions (x, Win, Wg)
  cvt3_bf16<<<(N4_X + N4_WIN + N4_WG + 255) / 256, 256, 0, stream>>>(
      x, x16, Win, Win16, Wg, Wg16);

  // 1) gx = x @ W_in^T, single dispatch, split output: gate16 | xbpre16
  gemm_bt8<false, true, true><<<dim3(G2 / TN, NT / TM), 512, 0, stream>>>(
      x16, Win16, gate16, xbpre16, nullptr, G2, D_M);
  // 2) depthwise causal conv -> xbc16 (2 ch/thread)
  conv_dw<<<dim3(H_M / 512, T_S, N_B), 256, 0, stream>>>(
      (const unsigned int*)xbpre16, cw, cb, (unsigned int*)xbc16);
  // 3) fg = xbc @ W_g^T + b_g  (overwrites xbpre16/x16/Win16 region)
  gemm_bt8<true, true, false><<<dim3(G2 / TN, NT / TM), 512, 0, stream>>>(
      xbc16, Wg16, fg16, nullptr, bg, G2, H_M);
  // Wout cvt into the now-dead Wg16 slot (after cA/cS)
  cvt_bf16<<<(D_M * H_M / 4 + 255) / 256, 256, 0, stream>>>(Wout, Wout16, D_M * H_M / 4);
  // 4) chunked linear scan + fused gelu(gate)*h (in-place over gate16), 2 ch/thread
  scan_A<<<dim3(H_M / 512, NCH, N_B), 256, 0, stream>>>(
      (const unsigned int*)fg16, (const unsigned int*)xbc16, fb, (float2*)cA, (float2*)cS);
  scan_C<<<dim3(H_M / 512, NCH, N_B), 256, 0, stream>>>(
      (const unsigned int*)fg16, (const unsigned int*)xbc16, fb,
      (const float2*)cA, (const float2*)cS, (unsigned int*)gate16);
  // 5) out = gh @ W_out^T  (fp32 out)
  gemm_bt8<false, false, false><<<dim3(D_M / TN, NT / TM), 512, 0, stream>>>(
      gate16, Wout16, out, nullptr, nullptr, D_M, H_M);
}

// Round 5
// 655.737 us; speedup vs baseline: 1.0319x; 1.0319x over previous
//
#include <hip/hip_runtime.h>
#include <stdint.h>
#include <math.h>

#define N_B 4
#define T_S 4096
#define D_M 1024
#define H_M 1536
#define NT  (N_B * T_S)   // 16384
#define G2  (2 * H_M)     // 3072
#define LCH 64            // timesteps per chunk
#define NCH 64            // chunks (LCH*NCH == T_S)

typedef __attribute__((ext_vector_type(8))) short short8;
typedef __attribute__((ext_vector_type(4))) float floatx4;

__device__ __forceinline__ unsigned short f2bf(float f) {
  unsigned u = __float_as_uint(f);
  u += 0x7fff + ((u >> 16) & 1);            // RNE
  return (unsigned short)(u >> 16);
}
__device__ __forceinline__ float bf2f(unsigned short u) {
  return __uint_as_float(((unsigned)u) << 16);
}
__device__ __forceinline__ float bf_lo(unsigned p) { return __uint_as_float(p << 16); }
__device__ __forceinline__ float bf_hi(unsigned p) { return __uint_as_float(p & 0xffff0000u); }
__device__ __forceinline__ unsigned bf_pack(float lo, float hi) {
  return ((unsigned)f2bf(lo)) | (((unsigned)f2bf(hi)) << 16);
}
__device__ __forceinline__ float sigmoidf_(float x) { return 1.f / (1.f + __expf(-x)); }
__device__ __forceinline__ float softplusf_(float x) {
  return (x > 20.f) ? x : log1pf(__expf(x));
}
__device__ __forceinline__ float geluf_(float x) {
  return 0.5f * x * (1.f + erff(x * 0.70710678118654752f));
}

// ---------------- zero-fill fallback (diagnostic if ws_size too small) ----------------
__global__ void zero_out(float* __restrict__ out, int n) {
  int i = blockIdx.x * 256 + threadIdx.x;
  if (i < n) out[i] = 0.f;
}

// ---------------- fused f32 -> bf16 conversion of x, Win, Wg (one launch) ----------------
#define N4_X   (NT * D_M / 4)          // 4,194,304
#define N4_WIN (G2 * D_M / 4)          //   786,432
#define N4_WG  (G2 * H_M / 4)          // 1,179,648
__global__ void cvt3_bf16(const float* __restrict__ x, unsigned short* __restrict__ x16,
                          const float* __restrict__ win, unsigned short* __restrict__ win16,
                          const float* __restrict__ wg, unsigned short* __restrict__ wg16) {
  int i = blockIdx.x * 256 + threadIdx.x;
  const float* in; unsigned short* out;
  if (i < N4_X)                { in = x;   out = x16; }
  else if (i < N4_X + N4_WIN)  { in = win; out = win16; i -= N4_X; }
  else if (i < N4_X + N4_WIN + N4_WG) { in = wg; out = wg16; i -= N4_X + N4_WIN; }
  else return;
  float4 v = ((const float4*)in)[i];
  ushort4 o;
  o.x = f2bf(v.x); o.y = f2bf(v.y); o.z = f2bf(v.z); o.w = f2bf(v.w);
  ((ushort4*)out)[i] = o;
}

__global__ void cvt_bf16(const float* __restrict__ in, unsigned short* __restrict__ out, int n4) {
  int i = blockIdx.x * 256 + threadIdx.x;
  if (i >= n4) return;
  float4 v = ((const float4*)in)[i];
  ushort4 o;
  o.x = f2bf(v.x); o.y = f2bf(v.y); o.z = f2bf(v.z); o.w = f2bf(v.w);
  ((ushort4*)out)[i] = o;
}

// ---------------- bf16 MFMA GEMM, 256x256 tile, deep-prefetch 4-phase schedule --------
// C[m,n] = sum_k A[m,k]*B[n,k] (+bias[n]).  512 threads = 8 waves (2 Mx4 N), BK=64.
// LDS 128 KiB: As/Bs[2 buf][2 row-half][128 rows x 64 k] bf16 (m201 geometry).
// r3 post-mortem: reads-at-top forced the vmcnt for tile t+1's kh0 into tile t's P4
// (1-2 phase lead -> stall); r2/r3 also ran MFMA (2483cy) and LDS reads (2300cy) nearly
// serial per tile (sum == measured 4970cy). r4: maximize overlap + prefetch depth:
//  - B-frags (bfr[4][2], 8 b128) read ONCE per tile at P1 and register-held -> B LDS
//    halves are dead after P1 -> B(t+2) restages into the CURRENT buffer at P2/P3
//    (6-7 phase lead); A(t+1) stages into the other buffer at P1/P2 (3-4 phase lead).
//  - ONE vmcnt per tile (boundary, vmcnt(4); vmcnt(0) only at last tile). Ledger: per
//    tile issues Ah0',Ah1' then Bh0'',Bh1'' (8 loads); at the next boundary the newest 4
//    (B'') may fly, the rest must land. Prologue {A(0),B(0),B(1)} = 12 loads, same wait.
//  - TWO barriers per tile: boundary (after vmcnt) + post-P1 (protects B[cur] reads from
//    the P2/P3 B'' restage). P2-P4 are fence-free: no lgkmcnt asm, no sched pins ->
//    compiler fine-grained waits slide ds_reads under MFMA clusters (the r2 proof that
//    compiler scheduling beats hand drains).
//  - quadrant phases: P_mq = {read af[2][2] for m-rows mq*32..+31, 16 MFMA (2m x 4n x 2kh)}.
//    acc[i=mq*2+ii][j] keeps the r2 row mapping (rows wr*128 + i*16) -> epilogue unchanged.
// Bank swizzle (r0-proven 0-conflict on 128B rows): 8 16B-groups/row, phys = logical ^
// (row&7); global source pre-swizzled g=(tid&7)^((tid>>3)&7), LDS dest linear (rule #21).
// XCD swizzle (r1-proven: FETCH 234->141 MB): bijective, nwg%8==0 for all shapes.
#define TM 256
#define TN 256

__device__ __forceinline__ void stage16(const unsigned short* g, unsigned short* l) {
  __builtin_amdgcn_global_load_lds((__attribute__((address_space(1))) void*)g,
                                   (__attribute__((address_space(3))) void*)l, 16, 0, 0);
}

template<bool BIAS, bool OUT_BF16, bool SPLIT>
__global__ __launch_bounds__(512, 2)
void gemm_bt8(const unsigned short* __restrict__ A,
              const unsigned short* __restrict__ B,
              void* __restrict__ Cv, void* __restrict__ Cv2,
              const float* __restrict__ bias,
              int N, int K) {
  __shared__ __align__(16) unsigned short As[2][2][8192];   // [buf][half][128*64]
  __shared__ __align__(16) unsigned short Bs[2][2][8192];
  const int tid  = threadIdx.x;
  const int lane = tid & 63;
  const int wave = tid >> 6;
  const int wr = wave >> 2;                  // 0..1  (M half of tile)
  const int wc = wave & 3;                   // 0..3  (N quarter of tile)

  // bijective XCD-aware block swizzle (nwg % 8 == 0 for all shapes used)
  const int gx  = gridDim.x;
  const int nwg = gx * gridDim.y;
  const int bid = blockIdx.y * gx + blockIdx.x;
  const int cpx = nwg >> 3;
  const int swz = (bid & 7) * cpx + (bid >> 3);
  const int bm = (swz / gx) * TM;
  const int bn = (swz % gx) * TN;

  floatx4 acc[8][4];
#pragma unroll
  for (int i = 0; i < 8; i++)
#pragma unroll
    for (int j = 0; j < 4; j++)
      acc[i][j] = (floatx4){0.f, 0.f, 0.f, 0.f};

  // ---- staging: one half = 128 rows x 64 k = 1024 x 16B chunks; thread does c=tid, tid+512.
  // chunk c -> row r=c>>3 (0..127), phys 16B-slot sl=c&7; fetches global k-group
  // g = sl ^ (r&7) = (tid&7)^((tid>>3)&7)  (invariant across the two chunks: +512 -> r+64).
  const int r0_ = tid >> 3;                  // 0..63
  const int g8  = ((tid & 7) ^ (r0_ & 7)) * 8;
  const unsigned short* Ag[2][2];            // [half][u]
  const unsigned short* Bg[2][2];
#pragma unroll
  for (int h = 0; h < 2; ++h)
#pragma unroll
    for (int u = 0; u < 2; ++u) {
      Ag[h][u] = A + (size_t)(bm + h * 128 + r0_ + 64 * u) * K + g8;
      Bg[h][u] = B + (size_t)(bn + h * 128 + r0_ + 64 * u) * K + g8;
    }
  const int ldd = tid * 8;                   // elem offset in half (u=0; +4096 for u=1)

#define STAGE_A(bu, h, kb) do { \
    stage16(Ag[h][0] + (kb), &As[bu][h][ldd]); \
    stage16(Ag[h][1] + (kb), &As[bu][h][ldd + 4096]); } while (0)
#define STAGE_B(bu, h, kb) do { \
    stage16(Bg[h][0] + (kb), &Bs[bu][h][ldd]); \
    stage16(Bg[h][1] + (kb), &Bs[bu][h][ldd + 4096]); } while (0)

  // ---- fragment reads: lane (fr, kq); phys 16B-group = (kh*4+kq) ^ (fr&7)
  const int fr = lane & 15;
  const int kq = lane >> 4;
  const int e8 = fr & 7;
  const int px0 = (kq ^ e8) * 8;             // kh0
  const int px1 = ((4 + kq) ^ e8) * 8;       // kh1
  const int arow = fr * 64;                  // + (mq*32 + ii*16)*64
  const int brow = ((wc & 1) * 64 + fr) * 64;   // + j*16*64

  const int nt = K >> 6;
  short8 af[2][2], bfr[4][2];

  // prologue: A(0),B(0) -> buf0; B(1) -> buf1 (A(1) staged during tile 0)
  STAGE_A(0, 0, 0); STAGE_A(0, 1, 0);
  STAGE_B(0, 0, 0); STAGE_B(0, 1, 0);
  if (nt > 1) { STAGE_B(1, 0, 64); STAGE_B(1, 1, 64); }

  for (int t = 0; t < nt; ++t) {
    const int par = t & 1;
    const int kn1 = (t + 1) << 6;
    const int kn2 = (t + 2) << 6;
    const bool s1 = (t + 1 < nt);
    const bool s2 = (t + 2 < nt);

    // boundary: oldest 8 outstanding (A(t),B(t) or A(t+1),B(t+1) in steady state) land;
    // newest 4 (B of the tile after) may stay in flight.
    if (s1) { asm volatile("s_waitcnt vmcnt(4)" ::: "memory"); }
    else    { asm volatile("s_waitcnt vmcnt(0)" ::: "memory"); }
    __builtin_amdgcn_s_barrier();

    const unsigned short* Ab = &As[par][wr][0];
    const unsigned short* Bb = &Bs[par][wc >> 1][0];

    // ---- P1: all B frags + quadrant mq0 ----
#pragma unroll
    for (int j = 0; j < 4; ++j) {
      bfr[j][0] = *(const short8*)(Bb + brow + j * 1024 + px0);
      bfr[j][1] = *(const short8*)(Bb + brow + j * 1024 + px1);
    }
#pragma unroll
    for (int ii = 0; ii < 2; ++ii) {
      af[ii][0] = *(const short8*)(Ab + arow + ii * 1024 + px0);
      af[ii][1] = *(const short8*)(Ab + arow + ii * 1024 + px1);
    }
    if (s1) STAGE_A(par ^ 1, 0, kn1);
    __builtin_amdgcn_s_setprio(1);
#pragma unroll
    for (int kh = 0; kh < 2; ++kh)
#pragma unroll
      for (int ii = 0; ii < 2; ++ii)
#pragma unroll
        for (int j = 0; j < 4; ++j)
          acc[ii][j] = __builtin_amdgcn_mfma_f32_16x16x32_bf16(af[ii][kh], bfr[j][kh], acc[ii][j], 0, 0, 0);
    __builtin_amdgcn_s_setprio(0);
    __builtin_amdgcn_s_barrier();   // protects B[par] halves before B'' restage below

    // ---- P2: quadrant mq1 ----
#pragma unroll
    for (int ii = 0; ii < 2; ++ii) {
      af[ii][0] = *(const short8*)(Ab + arow + (2048 + ii * 1024) + px0);
      af[ii][1] = *(const short8*)(Ab + arow + (2048 + ii * 1024) + px1);
    }
    if (s1) STAGE_A(par ^ 1, 1, kn1);
    if (s2) STAGE_B(par, 0, kn2);
    __builtin_amdgcn_s_setprio(1);
#pragma unroll
    for (int kh = 0; kh < 2; ++kh)
#pragma unroll
      for (int ii = 0; ii < 2; ++ii)
#pragma unroll
        for (int j = 0; j < 4; ++j)
          acc[2 + ii][j] = __builtin_amdgcn_mfma_f32_16x16x32_bf16(af[ii][kh], bfr[j][kh], acc[2 + ii][j], 0, 0, 0);
    __builtin_amdgcn_s_setprio(0);

    // ---- P3: quadrant mq2 (fence-free) ----
#pragma unroll
    for (int ii = 0; ii < 2; ++ii) {
      af[ii][0] = *(const short8*)(Ab + arow + (4096 + ii * 1024) + px0);
      af[ii][1] = *(const short8*)(Ab + arow + (4096 + ii * 1024) + px1);
    }
    if (s2) STAGE_B(par, 1, kn2);
    __builtin_amdgcn_s_setprio(1);
#pragma unroll
    for (int kh = 0; kh < 2; ++kh)
#pragma unroll
      for (int ii = 0; ii < 2; ++ii)
#pragma unroll
        for (int j = 0; j < 4; ++j)
          acc[4 + ii][j] = __builtin_amdgcn_mfma_f32_16x16x32_bf16(af[ii][kh], bfr[j][kh], acc[4 + ii][j], 0, 0, 0);
    __builtin_amdgcn_s_setprio(0);

    // ---- P4: quadrant mq3 (fence-free) ----
#pragma unroll
    for (int ii = 0; ii < 2; ++ii) {
      af[ii][0] = *(const short8*)(Ab + arow + (6144 + ii * 1024) + px0);
      af[ii][1] = *(const short8*)(Ab + arow + (6144 + ii * 1024) + px1);
    }
    __builtin_amdgcn_s_setprio(1);
#pragma unroll
    for (int kh = 0; kh < 2; ++kh)
#pragma unroll
      for (int ii = 0; ii < 2; ++ii)
#pragma unroll
        for (int j = 0; j < 4; ++j)
          acc[6 + ii][j] = __builtin_amdgcn_mfma_f32_16x16x32_bf16(af[ii][kh], bfr[j][kh], acc[6 + ii][j], 0, 0, 0);
    __builtin_amdgcn_s_setprio(0);
  }
#undef STAGE_A
#undef STAGE_B

  // C/D layout (m89-verified): col = lane&15, row = (lane>>4)*4 + reg
  // acc[i][j] rows = bm + wr*128 + i*16 (mq*2+ii == i keeps the r2 mapping).
  // stores row-major (j innermost): 64B C-line halves issued back-to-back (r2-proven).
  const int half  = SPLIT ? (N >> 1) : N;
  const bool hi   = SPLIT && (bn >= half);
  void* Cb        = hi ? Cv2 : Cv;
  const int coff  = hi ? half : 0;
  const int cn = lane & 15;
  const int rb = (lane >> 4) * 4;
  float bv[4];
#pragma unroll
  for (int j = 0; j < 4; ++j)
    bv[j] = BIAS ? bias[bn + wc * 64 + j * 16 + cn] : 0.f;
  const int col0 = bn + wc * 64 + cn - coff;
#pragma unroll
  for (int i = 0; i < 8; ++i) {
    const int row0 = bm + wr * 128 + i * 16 + rb;
#pragma unroll
    for (int r = 0; r < 4; ++r) {
      const size_t rowb = (size_t)(row0 + r) * half + col0;
#pragma unroll
      for (int j = 0; j < 4; ++j) {
        float v = acc[i][j][r] + bv[j];
        if (OUT_BF16) ((unsigned short*)Cb)[rowb + j * 16] = f2bf(v);
        else          ((float*)Cb)[rowb + j * 16] = v;
      }
    }
  }
}

// ---------------- depthwise causal conv (K=4) + bias, 2 channels/thread ----------------
__global__ void conv_dw(const unsigned int* __restrict__ xbpre2, const float* __restrict__ cw,
                        const float* __restrict__ cb, unsigned int* __restrict__ xbc2) {
  int i0 = blockIdx.x * 256 + threadIdx.x;       // pair index, 0..H_M/2-1
  int t = blockIdx.y;
  size_t nt = (size_t)blockIdx.z * T_S + t;
  const int h = 2 * i0;
  const float4 wa = ((const float4*)cw)[h];      // taps for channel h
  const float4 wb = ((const float4*)cw)[h + 1];  // taps for channel h+1
  const float2 cb2 = ((const float2*)cb)[i0];
  size_t base = nt * (H_M / 2) + i0;
  unsigned p0 = xbpre2[base];
  float aa = cb2.x + wa.w * bf_lo(p0);
  float ab = cb2.y + wb.w * bf_hi(p0);
  if (t >= 1) { unsigned p = xbpre2[base - H_M / 2];
    aa += wa.z * bf_lo(p); ab += wb.z * bf_hi(p); }
  if (t >= 2) { unsigned p = xbpre2[base - 2 * (size_t)(H_M / 2)];
    aa += wa.y * bf_lo(p); ab += wb.y * bf_hi(p); }
  if (t >= 3) { unsigned p = xbpre2[base - 3 * (size_t)(H_M / 2)];
    aa += wa.x * bf_lo(p); ab += wb.x * bf_hi(p); }
  xbc2[base] = bf_pack(aa, ab);
}

// ---------------- chunked linear scan (2 channels/thread) ----------------
__global__ void scan_A(const unsigned int* __restrict__ fg2, const unsigned int* __restrict__ xbc2,
                       const float* __restrict__ fb,
                       float2* __restrict__ cA2, float2* __restrict__ cS2) {
  int i0 = blockIdx.x * 256 + threadIdx.x;       // pair index
  int ch = blockIdx.y;
  int n = blockIdx.z;
  const float2 fb2 = ((const float2*)fb)[i0];
  const float c8a = 8.f * softplusf_(fb2.x);
  const float c8b = 8.f * softplusf_(fb2.y);
  float apa = 1.f, sa = 0.f, apb = 1.f, sb = 0.f;
  size_t r = (size_t)n * T_S + (size_t)ch * LCH;
  for (int i = 0; i < LCH; i++, r++) {
    unsigned pf = fg2[r * (G2 / 2) + i0];
    unsigned pi = fg2[r * (G2 / 2) + H_M / 2 + i0];
    unsigned px = xbc2[r * (H_M / 2) + i0];
    float alpha_a = __expf(-c8a * sigmoidf_(bf_lo(pf)));
    float alpha_b = __expf(-c8b * sigmoidf_(bf_hi(pf)));
    float beta_a = sqrtf(1.f - alpha_a * alpha_a + 1e-6f);
    float beta_b = sqrtf(1.f - alpha_b * alpha_b + 1e-6f);
    sa = alpha_a * sa + beta_a * sigmoidf_(bf_lo(pi)) * bf_lo(px);
    sb = alpha_b * sb + beta_b * sigmoidf_(bf_hi(pi)) * bf_hi(px);
    apa *= alpha_a;
    apb *= alpha_b;
  }
  size_t o = ((size_t)n * NCH + ch) * (H_M / 2) + i0;
  cA2[o] = make_float2(apa, apb);
  cS2[o] = make_float2(sa, sb);
}

// phase C: per-block prescan of chunk summaries (L2-hot) computes the carry-in,
// then replay with fused gelu(gate)*h written IN-PLACE over the gate buffer.
__global__ void scan_C(const unsigned int* __restrict__ fg2, const unsigned int* __restrict__ xbc2,
                       const float* __restrict__ fb,
                       const float2* __restrict__ cA2, const float2* __restrict__ cS2,
                       unsigned int* gateh2) {
  int i0 = blockIdx.x * 256 + threadIdx.x;
  int ch = blockIdx.y;
  int n = blockIdx.z;
  const float2 fb2 = ((const float2*)fb)[i0];
  const float c8a = 8.f * softplusf_(fb2.x);
  const float c8b = 8.f * softplusf_(fb2.y);
  float sa = 0.f, sb = 0.f;
  for (int c = 0; c < ch; c++) {
    size_t o = ((size_t)n * NCH + c) * (H_M / 2) + i0;
    float2 a = cA2[o], s = cS2[o];
    sa = a.x * sa + s.x;
    sb = a.y * sb + s.y;
  }
  size_t r = (size_t)n * T_S + (size_t)ch * LCH;
  for (int i = 0; i < LCH; i++, r++) {
    unsigned pf = fg2[r * (G2 / 2) + i0];
    unsigned pi = fg2[r * (G2 / 2) + H_M / 2 + i0];
    unsigned px = xbc2[r * (H_M / 2) + i0];
    float alpha_a = __expf(-c8a * sigmoidf_(bf_lo(pf)));
    float alpha_b = __expf(-c8b * sigmoidf_(bf_hi(pf)));
    float beta_a = sqrtf(1.f - alpha_a * alpha_a + 1e-6f);
    float beta_b = sqrtf(1.f - alpha_b * alpha_b + 1e-6f);
    sa = alpha_a * sa + beta_a * sigmoidf_(bf_lo(pi)) * bf_lo(px);
    sb = alpha_b * sb + beta_b * sigmoidf_(bf_hi(pi)) * bf_hi(px);
    unsigned pg = gateh2[r * (H_M / 2) + i0];
    gateh2[r * (H_M / 2) + i0] = bf_pack(geluf_(bf_lo(pg)) * sa, geluf_(bf_hi(pg)) * sb);
  }
}

// ---------------- launcher ----------------
// Workspace layout (S = NT*H_M*2 = 50,331,648 B; peak = 4S + 9.4 MB ≈ 210.8 MB):
//   [0,S)    gate16 (GEMM1 out, lo half) -> scan_C in-place -> gh16 (GEMM3 A)
//   [S,2S)   xbpre16 (GEMM1 out, hi half; conv in; dead after conv)
//   [S,3S)   fg16 (GEMM2 out, overwrites xbpre16 + x16/Win16)
//   [2S,..)  x16 (33.6MB) + Win16 (6.3MB), live only during GEMM1
//   [3S,4S)  xbc16 (conv out; dead after scan_C)
//   [4S,..)  Wg16 (9.4MB, dead after GEMM2) aliased by cA(1.5) + cS(1.5) + Wout16(3.1)
extern "C" void kernel_launch(void* const* d_in, const int* in_sizes, int n_in,
                              void* d_out, int out_size, void* d_ws, size_t ws_size,
                              hipStream_t stream) {
  const float* x    = (const float*)d_in[0];
  const float* Win  = (const float*)d_in[1];
  const float* cw   = (const float*)d_in[2];
  const float* cb   = (const float*)d_in[3];
  const float* Wg   = (const float*)d_in[4];
  const float* bg   = (const float*)d_in[5];
  const float* fb   = (const float*)d_in[6];
  const float* Wout = (const float*)d_in[7];
  float* out = (float*)d_out;
  (void)in_sizes; (void)n_in;

  const size_t S = (size_t)NT * H_M * 2;
  const size_t needed = 4 * S + (size_t)G2 * H_M * 2;
  if (ws_size < needed) {
    zero_out<<<(out_size + 255) / 256, 256, 0, stream>>>(out, out_size);
    return;
  }

  char* base = (char*)d_ws;
  unsigned short* gate16  = (unsigned short*)(base);            // becomes gh16 in-place
  unsigned short* xbpre16 = (unsigned short*)(base + S);
  unsigned short* fg16    = (unsigned short*)(base + S);        // [S,3S) after conv
  unsigned short* x16     = (unsigned short*)(base + 2 * S);    // live during GEMM1 only
  unsigned short* Win16   = (unsigned short*)(base + 2 * S + (size_t)NT * D_M * 2);
  unsigned short* xbc16   = (unsigned short*)(base + 3 * S);
  unsigned short* Wg16    = (unsigned short*)(base + 4 * S);    // dead after GEMM2
  float* cA    = (float*)(base + 4 * S);                        // aliases Wg16 (after GEMM2)
  float* cS    = cA + (size_t)N_B * NCH * H_M;
  unsigned short* Wout16  = (unsigned short*)(cS + (size_t)N_B * NCH * H_M);

  // fused bf16 conversions (x, Win, Wg)
  cvt3_bf16<<<(N4_X + N4_WIN + N4_WG + 255) / 256, 256, 0, stream>>>(
      x, x16, Win, Win16, Wg, Wg16);

  // 1) gx = x @ W_in^T, single dispatch, split output: gate16 | xbpre16
  gemm_bt8<false, true, true><<<dim3(G2 / TN, NT / TM), 512, 0, stream>>>(
      x16, Win16, gate16, xbpre16, nullptr, G2, D_M);
  // 2) depthwise causal conv -> xbc16 (2 ch/thread)
  conv_dw<<<dim3(H_M / 512, T_S, N_B), 256, 0, stream>>>(
      (const unsigned int*)xbpre16, cw, cb, (unsigned int*)xbc16);
  // 3) fg = xbc @ W_g^T + b_g  (overwrites xbpre16/x16/Win16 region)
  gemm_bt8<true, true, false><<<dim3(G2 / TN, NT / TM), 512, 0, stream>>>(
      xbc16, Wg16, fg16, nullptr, bg, G2, H_M);
  // Wout cvt into the now-dead Wg16 slot (after cA/cS)
  cvt_bf16<<<(D_M * H_M / 4 + 255) / 256, 256, 0, stream>>>(Wout, Wout16, D_M * H_M / 4);
  // 4) chunked linear scan + fused gelu(gate)*h (in-place over gate16), 2 ch/thread
  scan_A<<<dim3(H_M / 512, NCH, N_B), 256, 0, stream>>>(
      (const unsigned int*)fg16, (const unsigned int*)xbc16, fb, (float2*)cA, (float2*)cS);
  scan_C<<<dim3(H_M / 512, NCH, N_B), 256, 0, stream>>>(
      (const unsigned int*)fg16, (const unsigned int*)xbc16, fb,
      (const float2*)cA, (const float2*)cS, (unsigned int*)gate16);
  // 5) out = gh @ W_out^T  (fp32 out)
  gemm_bt8<false, false, false><<<dim3(D_M / TN, NT / TM), 512, 0, stream>>>(
      gate16, Wout16, out, nullptr, nullptr, D_M, H_M);
}